// Round 1
// baseline (38.782 us; speedup 1.0000x reference)
//
#include <hip/hip_runtime.h>
#include <math.h>

// Problem constants (from reference)
constexpr int kNB   = 16;
constexpr int kNA   = 5;
constexpr int kNC   = 80;
constexpr int kNH   = 64;
constexpr int kNW   = 64;
constexpr int kMAXT = 50;
constexpr int kCH    = 5 + kNC;          // 85 channels per anchor
constexpr int kPLANE = kNH * kNW;        // 4096
constexpr int kCELLS_B = kNA * kPLANE;   // 20480 cells per batch
constexpr int kNTOT  = kNB * kCELLS_B;   // 327680
constexpr float kTHRESH = 0.6f;
constexpr float kNOOBJ  = 1.0f;
constexpr float kOBJ    = 5.0f;

// Per-target record layout (12 floats):
// 0: valid, 1: cell (within-batch, as float), 2..5: gx,gy,gw,gh,
// 6..9: t0,t1,t2,t3, 10: tconf (iou_best), 11: tcls (as float)
constexpr int kRECF = 12;

__device__ __forceinline__ float sigf(float x) { return 1.0f / (1.0f + expf(-x)); }

// -------------------- Kernel 1: per-target records --------------------
__global__ void k_targets(const float* __restrict__ out,
                          const float* __restrict__ target,
                          const float* __restrict__ anchors,
                          float* __restrict__ rec) {
    int idx = blockIdx.x * blockDim.x + threadIdx.x;
    if (idx >= kNB * kMAXT) return;
    int b = idx / kMAXT, t = idx % kMAXT;
    const float* tb = target + b * kMAXT * 5;

    // valid = cumprod(x != 0) prefix
    bool valid = true;
    for (int tp = 0; tp <= t; ++tp) valid = valid && (tb[tp * 5 + 1] != 0.0f);

    float* r = rec + idx * kRECF;
    if (!valid) { r[0] = 0.0f; return; }

    float gcls = tb[t * 5 + 0];
    float gx = tb[t * 5 + 1] * kNW;
    float gy = tb[t * 5 + 2] * kNH;
    float gw = tb[t * 5 + 3] * kNW;
    float gh = tb[t * 5 + 4] * kNH;

    // best anchor by area-IoU (first max wins, like jnp.argmax)
    int bn = 0; float best = -1.0f;
    for (int n = 0; n < kNA; ++n) {
        float aw = anchors[n * 2 + 0], ah = anchors[n * 2 + 1];
        float inter = fminf(gw, aw) * fminf(gh, ah);
        float uni = gw * gh + aw * ah - inter;
        float ratio = inter / uni;
        if (ratio > best) { best = ratio; bn = n; }
    }

    // cast-then-clip (ref: clip(gx.astype(int32), 0, NW-1))
    int gi = (int)gx; gi = gi < 0 ? 0 : (gi > kNW - 1 ? kNW - 1 : gi);
    int gj = (int)gy; gj = gj < 0 ? 0 : (gj > kNH - 1 ? kNH - 1 : gj);
    int cell = bn * kPLANE + gj * kNW + gi;

    float aw = anchors[bn * 2 + 0], ah = anchors[bn * 2 + 1];
    const float* ob = out + ((size_t)(b * kNA + bn) * kCH) * kPLANE + gj * kNW + gi;
    float o0 = ob[0 * kPLANE], o1 = ob[1 * kPLANE];
    float o2 = ob[2 * kPLANE], o3 = ob[3 * kPLANE];

    float px = sigf(o0) + (float)gi;
    float py = sigf(o1) + (float)gj;
    float pw = expf(o2) * aw;
    float ph = expf(o3) * ah;

    // IoU(gt, matched pred)
    float cw  = fminf(gx + 0.5f * gw, px + 0.5f * pw) - fmaxf(gx - 0.5f * gw, px - 0.5f * pw);
    float chh = fminf(gy + 0.5f * gh, py + 0.5f * ph) - fmaxf(gy - 0.5f * gh, py - 0.5f * ph);
    float inter = fmaxf(cw, 0.0f) * fmaxf(chh, 0.0f);
    float uni = gw * gh + pw * ph - inter;
    float iou = (inter > 0.0f) ? inter / uni : 0.0f;

    r[0] = 1.0f;
    r[1] = (float)cell;
    r[2] = gx; r[3] = gy; r[4] = gw; r[5] = gh;
    r[6] = gx - (float)gi;
    r[7] = gy - (float)gj;
    r[8] = logf(gw / aw);
    r[9] = logf(gh / ah);
    r[10] = iou;
    r[11] = gcls;
}

// -------------------- Kernel 2: per-cell loss --------------------
__global__ __launch_bounds__(256) void k_loss(const float* __restrict__ out,
                                              const float* __restrict__ anchors,
                                              const float* __restrict__ rec,
                                              float* __restrict__ partials) {
    __shared__ float srec[kMAXT * kRECF];
    __shared__ int snv;
    __shared__ float wsum[4];

    int gidx = blockIdx.x * 256 + threadIdx.x;
    int b = gidx / kCELLS_B;
    int within = gidx % kCELLS_B;
    int a = within / kPLANE;
    int remp = within % kPLANE;
    int j = remp / kNW, i = remp % kNW;

    // stage this batch's target records (whole block shares b)
    for (int k = threadIdx.x; k < kMAXT * kRECF; k += 256)
        srec[k] = rec[b * kMAXT * kRECF + k];
    if (threadIdx.x == 0) {
        int nv = 0;
        while (nv < kMAXT && srec[nv * kRECF] != 0.0f) ++nv;  // valid is a prefix
        snv = nv;
    }
    __syncthreads();
    int nv = snv;

    // decode this cell's prediction
    const float* ob = out + ((size_t)(b * kNA + a) * kCH) * kPLANE + remp;
    float tx = sigf(ob[0 * kPLANE]);
    float ty = sigf(ob[1 * kPLANE]);
    float tw = ob[2 * kPLANE];
    float th = ob[3 * kPLANE];
    float conf = sigf(ob[4 * kPLANE]);

    float aw = anchors[a * 2 + 0], ah = anchors[a * 2 + 1];
    float px = tx + (float)i, py = ty + (float)j;
    float pw = expf(tw) * aw, ph = expf(th) * ah;
    float px1 = px - 0.5f * pw, px2 = px + 0.5f * pw;
    float py1 = py - 0.5f * ph, py2 = py + 0.5f * ph;
    float parea = pw * ph;

    int mycell = a * kPLANE + remp;
    float maxiou = 0.0f;
    int match = -1;  // last matching t wins (mimics scatter last-write)
    for (int t = 0; t < nv; ++t) {
        const float* r = srec + t * kRECF;
        float gx = r[2], gy = r[3], gw = r[4], gh = r[5];
        float cw  = fminf(gx + 0.5f * gw, px2) - fmaxf(gx - 0.5f * gw, px1);
        float chh = fminf(gy + 0.5f * gh, py2) - fmaxf(gy - 0.5f * gh, py1);
        float inter = fmaxf(cw, 0.0f) * fmaxf(chh, 0.0f);
        float uni = gw * gh + parea - inter;
        float iou = (inter > 0.0f) ? inter / uni : 0.0f;
        maxiou = fmaxf(maxiou, iou);
        if ((int)r[1] == mycell) match = t;
    }

    float t0 = 0.5f, t1 = 0.5f, t2 = 0.0f, t3 = 0.0f, tconf = 0.0f;
    float cmask;
    float lcls = 0.0f;
    if (match >= 0) {
        const float* r = srec + match * kRECF;
        t0 = r[6]; t1 = r[7]; t2 = r[8]; t3 = r[9]; tconf = r[10];
        cmask = kOBJ;
        int tcls = (int)r[11];
        // CE = logsumexp(logits) - logits[tcls]
        float mx = -INFINITY;
        for (int c = 0; c < kNC; ++c) mx = fmaxf(mx, ob[(5 + c) * kPLANE]);
        float s = 0.0f;
        for (int c = 0; c < kNC; ++c) s += expf(ob[(5 + c) * kPLANE] - mx);
        lcls = (logf(s) + mx) - ob[(5 + tcls) * kPLANE];
    } else {
        cmask = (maxiou > kTHRESH) ? 0.0f : kNOOBJ;
    }

    float dx = tx - t0, dy = ty - t1, dw = tw - t2, dh = th - t3;
    float dcf = conf - tconf;
    float loss = 0.5f * (dx * dx + dy * dy + dw * dw + dh * dh)
               + 0.5f * cmask * dcf * dcf
               + lcls;

    // deterministic block reduction: wave shuffle then LDS across 4 waves
    float v = loss;
    #pragma unroll
    for (int off = 32; off > 0; off >>= 1) v += __shfl_down(v, off, 64);
    if ((threadIdx.x & 63) == 0) wsum[threadIdx.x >> 6] = v;
    __syncthreads();
    if (threadIdx.x == 0)
        partials[blockIdx.x] = wsum[0] + wsum[1] + wsum[2] + wsum[3];
}

// -------------------- Kernel 3: deterministic final sum --------------------
__global__ void k_final(const float* __restrict__ partials, float* __restrict__ outv, int n) {
    __shared__ float red[256];
    float s = 0.0f;
    for (int k = threadIdx.x; k < n; k += 256) s += partials[k];
    red[threadIdx.x] = s;
    __syncthreads();
    for (int off = 128; off > 0; off >>= 1) {
        if (threadIdx.x < off) red[threadIdx.x] += red[threadIdx.x + off];
        __syncthreads();
    }
    if (threadIdx.x == 0) outv[0] = red[0];
}

extern "C" void kernel_launch(void* const* d_in, const int* in_sizes, int n_in,
                              void* d_out, int out_size, void* d_ws, size_t ws_size,
                              hipStream_t stream) {
    const float* output  = (const float*)d_in[0];
    const float* target  = (const float*)d_in[1];
    const float* anchors = (const float*)d_in[2];

    float* rec = (float*)d_ws;                       // 800 * 12 floats
    float* partials = rec + kNB * kMAXT * kRECF;     // 1280 floats

    k_targets<<<(kNB * kMAXT + 255) / 256, 256, 0, stream>>>(output, target, anchors, rec);
    k_loss<<<kNTOT / 256, 256, 0, stream>>>(output, anchors, rec, partials);
    k_final<<<1, 256, 0, stream>>>(partials, (float*)d_out, kNTOT / 256);
}

// Round 2
// 20.785 us; speedup vs baseline: 1.8659x; 1.8659x over previous
//
#include <hip/hip_runtime.h>
#include <math.h>

// Problem constants
constexpr int kNB   = 16;
constexpr int kNA   = 5;
constexpr int kNC   = 80;
constexpr int kNH   = 64;
constexpr int kNW   = 64;
constexpr int kMAXT = 50;
constexpr int kCH    = 5 + kNC;          // 85
constexpr int kPLANE = kNH * kNW;        // 4096
constexpr int kCELLS_B = kNA * kPLANE;   // 20480
constexpr int kNTOT  = kNB * kCELLS_B;   // 327680
constexpr int kMAIN_BLOCKS = kNTOT / 256;        // 1280
constexpr int kTOT_BLOCKS  = kMAIN_BLOCKS + kNB; // 1296 (16 CE blocks appended)
constexpr float kOBJ = 5.0f;

// Record layout (16 floats, 16B-aligned for ds_read_b128):
//  [0..3]  x1, x2, y1, y2          (expanded gt box)       -> b128 in hot loop
//  [4]     0.6 * garea             (for divide-free iou>0.6)
//  [5]     cell (int bits)                                   -> b64 in hot loop
//  [6..7]  pad
//  [8..11] t0, t1, t2, t3                                    -> b128 on match
//  [12]    tconf (iou_best)
//  [13]    tcls (float)
//  [14]    owner flag (1.0 = last target writing this cell)
//  [15]    pad
constexpr int kRECF = 16;

__device__ __forceinline__ float frcp(float x) { return __builtin_amdgcn_rcpf(x); }
__device__ __forceinline__ float fsig(float x) { return frcp(1.0f + __expf(-x)); }

// -------------------- Kernel 1: per-target records (16 blocks x 64) --------------------
__global__ __launch_bounds__(64) void k_targets(const float* __restrict__ out,
                                                const float* __restrict__ target,
                                                const float* __restrict__ anchors,
                                                float* __restrict__ rec,
                                                int* __restrict__ nvArr) {
    int b = blockIdx.x, t = threadIdx.x;
    float c0 = 0.f, x = 0.f, y = 0.f, w = 0.f, h = 0.f;
    if (t < kMAXT) {
        const float* tp = target + (b * kMAXT + t) * 5;
        c0 = tp[0]; x = tp[1]; y = tp[2]; w = tp[3]; h = tp[4];
    }
    // validity prefix via ballot: nv = index of first zero-x (lanes >=50 have x==0)
    unsigned long long m = __ballot(x != 0.0f);
    unsigned long long inv = ~m;
    int nv = inv ? (int)__builtin_ctzll(inv) : 64;
    if (nv > kMAXT) nv = kMAXT;
    if (t == 0) nvArr[b] = nv;

    __shared__ int scell[64];
    int cell = -1, gi = 0, gj = 0, bn = 0;
    float gx = 0, gy = 0, gw = 0, gh = 0, aw = 1, ah = 1;
    if (t < nv) {
        gx = x * kNW; gy = y * kNH; gw = w * kNW; gh = h * kNH;
        // best anchor by area-IoU, first max wins
        float best = -1.0f;
        for (int n = 0; n < kNA; ++n) {
            float aw_ = anchors[2 * n], ah_ = anchors[2 * n + 1];
            float inter = fminf(gw, aw_) * fminf(gh, ah_);
            float uni = gw * gh + aw_ * ah_ - inter;
            float ratio = inter / uni;
            if (ratio > best) { best = ratio; bn = n; }
        }
        aw = anchors[2 * bn]; ah = anchors[2 * bn + 1];
        gi = (int)gx; gi = gi < 0 ? 0 : (gi > kNW - 1 ? kNW - 1 : gi);
        gj = (int)gy; gj = gj < 0 ? 0 : (gj > kNH - 1 ? kNH - 1 : gj);
        cell = bn * kPLANE + gj * kNW + gi;
    }
    scell[t] = cell;
    __syncthreads();

    if (t < nv) {
        // owner = last target writing this cell (scatter last-write-wins)
        bool owner = true;
        for (int t2 = t + 1; t2 < nv; ++t2)
            if (scell[t2] == cell) owner = false;

        // matched prediction + IoU (exact divide: only 800 of these)
        const float* ob = out + ((size_t)(b * kNA + bn) * kCH) * kPLANE + (cell & (kPLANE - 1));
        float px = fsig(ob[0]) + (float)gi;
        float py = fsig(ob[kPLANE]) + (float)gj;
        float pw = __expf(ob[2 * kPLANE]) * aw;
        float ph = __expf(ob[3 * kPLANE]) * ah;
        float cw  = fminf(gx + 0.5f * gw, px + 0.5f * pw) - fmaxf(gx - 0.5f * gw, px - 0.5f * pw);
        float chh = fminf(gy + 0.5f * gh, py + 0.5f * ph) - fmaxf(gy - 0.5f * gh, py - 0.5f * ph);
        float inter = fmaxf(cw, 0.f) * fmaxf(chh, 0.f);
        float uni = gw * gh + pw * ph - inter;
        float iou = (inter > 0.f) ? inter / uni : 0.f;

        float* r = rec + (b * kMAXT + t) * kRECF;
        r[0]  = gx - 0.5f * gw;  r[1]  = gx + 0.5f * gw;
        r[2]  = gy - 0.5f * gh;  r[3]  = gy + 0.5f * gh;
        r[4]  = 0.6f * gw * gh;  r[5]  = __int_as_float(cell);
        r[6]  = 0.f;             r[7]  = 0.f;
        r[8]  = gx - (float)gi;  r[9]  = gy - (float)gj;
        r[10] = __logf(gw / aw); r[11] = __logf(gh / ah);
        r[12] = iou;             r[13] = c0;
        r[14] = owner ? 1.f : 0.f; r[15] = 0.f;
    }
}

// -------------------- Kernel 2: per-cell loss (1280 main + 16 CE blocks) ----------------
__global__ __launch_bounds__(256) void k_main(const float* __restrict__ out,
                                              const float* __restrict__ anchors,
                                              const float* __restrict__ rec,
                                              const int* __restrict__ nvArr,
                                              float* __restrict__ partials) {
    __shared__ float wred[4];

    if (blockIdx.x >= kMAIN_BLOCKS) {
        // ---- CE blocks: one per batch, wave-per-target, lanes cover 80 classes ----
        int b = blockIdx.x - kMAIN_BLOCKS;
        int nv = nvArr[b];
        int wid = threadIdx.x >> 6, lane = threadIdx.x & 63;
        float acc = 0.f;
        for (int t = wid; t < nv; t += 4) {
            const float* r = rec + (b * kMAXT + t) * kRECF;
            if (r[14] == 0.f) continue;          // not owner -> CE counted at later duplicate
            int cell = __float_as_int(r[5]);
            int bn = cell >> 12, pix = cell & (kPLANE - 1);
            int tcls = (int)r[13];
            const float* lg = out + ((size_t)(b * kNA + bn) * kCH + 5) * kPLANE + pix;
            float v0 = lg[(size_t)lane * kPLANE];
            float v1 = (lane < kNC - 64) ? lg[(size_t)(64 + lane) * kPLANE] : -INFINITY;
            float mx = fmaxf(v0, v1);
            #pragma unroll
            for (int off = 32; off > 0; off >>= 1) mx = fmaxf(mx, __shfl_xor(mx, off, 64));
            float s = __expf(v0 - mx) + ((lane < kNC - 64) ? __expf(v1 - mx) : 0.f);
            #pragma unroll
            for (int off = 32; off > 0; off >>= 1) s += __shfl_xor(s, off, 64);
            float lt = lg[(size_t)tcls * kPLANE];
            if (lane == 0) acc += __logf(s) + mx - lt;
        }
        if ((threadIdx.x & 63) == 0) wred[threadIdx.x >> 6] = acc;
        __syncthreads();
        if (threadIdx.x == 0)
            partials[blockIdx.x] = wred[0] + wred[1] + wred[2] + wred[3];
        return;
    }

    // ---- main per-cell blocks ----
    __shared__ __align__(16) float srec[kMAXT * kRECF];
    int b = blockIdx.x / (kCELLS_B / 256);   // 80 blocks per batch
    int nv = nvArr[b];
    for (int k = threadIdx.x; k < nv * kRECF; k += 256)
        srec[k] = rec[b * kMAXT * kRECF + k];
    __syncthreads();

    int gidx = blockIdx.x * 256 + threadIdx.x;
    int within = gidx % kCELLS_B;
    int a = within / kPLANE;
    int remp = within & (kPLANE - 1);
    int i = remp & (kNW - 1), j = remp >> 6;

    const float* ob = out + ((size_t)(b * kNA + a) * kCH) * kPLANE + remp;
    float tx   = fsig(ob[0]);
    float ty   = fsig(ob[kPLANE]);
    float tw   = ob[2 * kPLANE];
    float th   = ob[3 * kPLANE];
    float conf = fsig(ob[4 * kPLANE]);

    float aw = anchors[2 * a], ah = anchors[2 * a + 1];
    float pw = __expf(tw) * aw, ph = __expf(th) * ah;
    float px = tx + (float)i, py = ty + (float)j;
    float px1 = px - 0.5f * pw, px2 = px + 0.5f * pw;
    float py1 = py - 0.5f * ph, py2 = py + 0.5f * ph;
    float p06 = 0.6f * pw * ph;
    int mycell = a * kPLANE + remp;

    // divide-free: iou>0.6  <=>  1.6*inter > 0.6*(garea+parea)
    float flag = -1.f;
    int match = -1;                       // last matching t wins (scatter semantics)
    for (int t = 0; t < nv; ++t) {
        const float4 bx = *reinterpret_cast<const float4*>(srec + t * kRECF);
        const float2 gc = *reinterpret_cast<const float2*>(srec + t * kRECF + 4);
        float cw  = fminf(bx.y, px2) - fmaxf(bx.x, px1);
        float chh = fminf(bx.w, py2) - fmaxf(bx.z, py1);
        float inter = fmaxf(cw, 0.f) * fmaxf(chh, 0.f);
        flag = fmaxf(flag, fmaf(1.6f, inter, -(gc.x + p06)));
        match = (__float_as_int(gc.y) == mycell) ? t : match;
    }

    float t0 = 0.5f, t1 = 0.5f, t2 = 0.f, t3 = 0.f, tconf = 0.f, cmask;
    if (match >= 0) {
        const float4 tt = *reinterpret_cast<const float4*>(srec + match * kRECF + 8);
        t0 = tt.x; t1 = tt.y; t2 = tt.z; t3 = tt.w;
        tconf = srec[match * kRECF + 12];
        cmask = kOBJ;
    } else {
        cmask = (flag > 0.f) ? 0.f : 1.f;
    }

    float dx = tx - t0, dy = ty - t1, dw = tw - t2, dh = th - t3, dc = conf - tconf;
    float loss = 0.5f * (dx * dx + dy * dy + dw * dw + dh * dh)
               + 0.5f * cmask * dc * dc;

    #pragma unroll
    for (int off = 32; off > 0; off >>= 1) loss += __shfl_down(loss, off, 64);
    if ((threadIdx.x & 63) == 0) wred[threadIdx.x >> 6] = loss;
    __syncthreads();
    if (threadIdx.x == 0)
        partials[blockIdx.x] = wred[0] + wred[1] + wred[2] + wred[3];
}

// -------------------- Kernel 3: deterministic final sum --------------------
__global__ __launch_bounds__(256) void k_final(const float* __restrict__ partials,
                                               float* __restrict__ outv, int n) {
    __shared__ float red[256];
    float s = 0.f;
    for (int k = threadIdx.x; k < n; k += 256) s += partials[k];
    red[threadIdx.x] = s;
    __syncthreads();
    for (int off = 128; off > 0; off >>= 1) {
        if (threadIdx.x < off) red[threadIdx.x] += red[threadIdx.x + off];
        __syncthreads();
    }
    if (threadIdx.x == 0) outv[0] = red[0];
}

extern "C" void kernel_launch(void* const* d_in, const int* in_sizes, int n_in,
                              void* d_out, int out_size, void* d_ws, size_t ws_size,
                              hipStream_t stream) {
    const float* output  = (const float*)d_in[0];
    const float* target  = (const float*)d_in[1];
    const float* anchors = (const float*)d_in[2];

    float* rec      = (float*)d_ws;                         // 16*50*16 = 12800 floats
    int*   nvArr    = (int*)(rec + kNB * kMAXT * kRECF);    // 16 ints
    float* partials = (float*)(nvArr + kNB);                // 1296 floats

    k_targets<<<kNB, 64, 0, stream>>>(output, target, anchors, rec, nvArr);
    k_main<<<kTOT_BLOCKS, 256, 0, stream>>>(output, anchors, rec, nvArr, partials);
    k_final<<<1, 256, 0, stream>>>(partials, (float*)d_out, kTOT_BLOCKS);
}